// Round 6
// baseline (677.380 us; speedup 1.0000x reference)
//
#include <hip/hip_runtime.h>
#include <hip/hip_fp16.h>
#include <stdint.h>

// ---------------------------------------------------------------------------
// GNN forward: GCN -> SAGE(+res) -> SAGE(+res) -> lin -> GCN
// Strategy: aggregate-first (linearity), CSR built once per call, fused dense
// 64x64 GEMM epilogues, fp16 gather mirror.
// R2: bounded unroll + launch_bounds(256,2) fixed GEMM spill.
// R3: quarter-wave float4 gather (16 rows in flight/wave).
// R4: fp16 gather mirror.
// R5: counting-sort bucket scatter (edges read 2x, not 8x).
// R6a: TRUE XCD affinity for slice passes via s_getreg(HW_REG_XCC_ID) + per-
//      slice chunk work-stealing. R5 showed WRITE_SIZE still 10x ideal: the
//      bid&7->XCD assumption doesn't hold, slices were dirtied in multiple
//      L2s. Correctness is independent of the hwreg value (all blocks walk
//      all slices; per-slice atomic cursors hand out chunks exactly once).
// R6b: layers 3a+3b fused into k_gemm_tri (t3 never hits memory).
// ---------------------------------------------------------------------------

typedef unsigned long long ull;

#define NSL 8
#define BKT_BLOCKS 512
#define SLICE_BLOCKS 1024
#define CHUNK 4096

__device__ __forceinline__ int get_xcd(){
  // s_getreg_b32 hwreg(id=20 XCC_ID, offset=0, size=32); mask to 0..7.
  // Perf-only hint: correctness never depends on this value.
  return (int)(__builtin_amdgcn_s_getreg((31u << 11) | 20u) & 7u);
}

__device__ __forceinline__ void fma4(float4& a, float s, const float4& w){
  a.x = fmaf(s, w.x, a.x);
  a.y = fmaf(s, w.y, a.y);
  a.z = fmaf(s, w.z, a.z);
  a.w = fmaf(s, w.w, a.w);
}

__device__ __forceinline__ ushort4 pack_h4(float4 v){
  ushort4 u;
  u.x = __half_as_ushort(__float2half(v.x));
  u.y = __half_as_ushort(__float2half(v.y));
  u.z = __half_as_ushort(__float2half(v.z));
  u.w = __half_as_ushort(__float2half(v.w));
  return u;
}

__device__ __forceinline__ float4 unpack_h4(ushort4 u){
  return make_float4(__half2float(__ushort_as_half(u.x)),
                     __half2float(__ushort_as_half(u.y)),
                     __half2float(__ushort_as_half(u.z)),
                     __half2float(__ushort_as_half(u.w)));
}

// ---------------- CSR build: bucket scatter ----------------
// 8 slices by dst (slice = dst / SL). Each block owns a contiguous edge chunk;
// pass 1 builds an LDS histogram, one global reservation per slice, pass 2
// scatters packed (src<<32|dst) into per-slice buckets at LDS cursors.

__global__ __launch_bounds__(256) void k_bucket(const int* __restrict__ src,
                                                const int* __restrict__ dst,
                                                ull* __restrict__ bkt,
                                                int* __restrict__ bcnt,
                                                int E, int SL, int cap){
  __shared__ int hist[NSL];
  __shared__ int cur[NSL];
  int t = threadIdx.x;
  int chunk = (E + BKT_BLOCKS - 1) / BKT_BLOCKS;
  int e0 = blockIdx.x * chunk;
  int e1 = min(E, e0 + chunk);
  if (t < NSL) hist[t] = 0;
  __syncthreads();
  for (int e = e0 + t; e < e1; e += 256){
    int s = dst[e] / SL;
    atomicAdd(&hist[s], 1);
  }
  __syncthreads();
  if (t < NSL){
    int h = hist[t];
    cur[t] = h ? atomicAdd(&bcnt[t], h) : 0;
  }
  __syncthreads();
  for (int e = e0 + t; e < e1; e += 256){
    int d = dst[e];
    int s = d / SL;
    int pos = atomicAdd(&cur[s], 1);
    if (pos < cap)
      bkt[(size_t)s * cap + pos] = ((ull)(unsigned)src[e] << 32) | (unsigned)d;
  }
}

// XCD-affine slice pass: block starts at its OWN XCD's slice, work-steals
// chunks via per-slice cursors, then drains remaining slices (correctness
// never depends on the xcd value).

__global__ __launch_bounds__(256) void k_deg2(const ull* __restrict__ bkt,
                                              const int* __restrict__ bcnt,
                                              int* __restrict__ work,
                                              int* __restrict__ deg, int cap){
  __shared__ int sh_c;
  int t = threadIdx.x;
  int xcd = get_xcd();
  for (int ss = 0; ss < NSL; ++ss){
    int s = (xcd + ss) & (NSL - 1);
    int cnt = min(bcnt[s], cap);
    int nch = (cnt + CHUNK - 1) / CHUNK;
    const ull* b = bkt + (size_t)s * cap;
    for (;;){
      if (t == 0) sh_c = atomicAdd(&work[s], 1);
      __syncthreads();
      int c = sh_c;
      __syncthreads();
      if (c >= nch) break;
      int i0 = c * CHUNK, i1 = min(cnt, i0 + CHUNK);
      for (int i = i0 + t; i < i1; i += 256){
        int d = (int)(b[i] & 0xffffffffu);
        atomicAdd(&deg[d], 1);
      }
    }
  }
}

__global__ __launch_bounds__(256) void k_fill2(const ull* __restrict__ bkt,
                                               const int* __restrict__ bcnt,
                                               const int* __restrict__ offs,
                                               int* __restrict__ work,
                                               int* __restrict__ deg,
                                               int* __restrict__ csr, int cap){
  __shared__ int sh_c;
  int t = threadIdx.x;
  int xcd = get_xcd();
  for (int ss = 0; ss < NSL; ++ss){
    int s = (xcd + ss) & (NSL - 1);
    int cnt = min(bcnt[s], cap);
    int nch = (cnt + CHUNK - 1) / CHUNK;
    const ull* b = bkt + (size_t)s * cap;
    for (;;){
      if (t == 0) sh_c = atomicAdd(&work[s], 1);
      __syncthreads();
      int c = sh_c;
      __syncthreads();
      if (c >= nch) break;
      int i0 = c * CHUNK, i1 = min(cnt, i0 + CHUNK);
      for (int i = i0 + t; i < i1; i += 256){
        ull pk = b[i];
        int d  = (int)(pk & 0xffffffffu);
        int sr = (int)(pk >> 32);
        int p  = offs[d] + atomicSub(&deg[d], 1) - 1;
        csr[p] = sr;
      }
    }
  }
}

// ---------------- scans (+prep fused into scanC) ----------------

__global__ __launch_bounds__(256) void k_scanA(const int* __restrict__ deg,
                                               int* __restrict__ bsum, int n){
  __shared__ int sm[256];
  int b = blockIdx.x, t = threadIdx.x;
  int base = b * 1024 + t * 4;
  int s = 0;
  #pragma unroll
  for (int u = 0; u < 4; ++u){ int i = base + u; if (i < n) s += deg[i]; }
  sm[t] = s; __syncthreads();
  for (int off = 128; off > 0; off >>= 1){
    if (t < off) sm[t] += sm[t + off];
    __syncthreads();
  }
  if (t == 0) bsum[b] = sm[0];
}

__global__ void k_scanB(const int* __restrict__ bsum, int* __restrict__ bscan,
                        int* __restrict__ offs, int nb, int n){
  if (blockIdx.x == 0 && threadIdx.x == 0){
    int run = 0;
    for (int i = 0; i < nb; ++i){ bscan[i] = run; run += bsum[i]; }
    offs[n] = run;
  }
}

__global__ __launch_bounds__(256) void k_scanC(const int* __restrict__ deg,
                                               const int* __restrict__ bscan,
                                               int* __restrict__ offs,
                                               float* __restrict__ dis,
                                               float* __restrict__ invd, int n){
  __shared__ int sm[256];
  int b = blockIdx.x, t = threadIdx.x;
  int base = b * 1024 + t * 4;
  int v0 = (base + 0 < n) ? deg[base + 0] : 0;
  int v1 = (base + 1 < n) ? deg[base + 1] : 0;
  int v2 = (base + 2 < n) ? deg[base + 2] : 0;
  int v3 = (base + 3 < n) ? deg[base + 3] : 0;
  int ts = v0 + v1 + v2 + v3;
  sm[t] = ts; __syncthreads();
  #pragma unroll
  for (int off = 1; off < 256; off <<= 1){
    int add = (t >= off) ? sm[t - off] : 0;
    __syncthreads();
    sm[t] += add;
    __syncthreads();
  }
  int excl = sm[t] - ts;
  int run = bscan[b] + excl;
  if (base + 0 < n) offs[base + 0] = run; run += v0;
  if (base + 1 < n) offs[base + 1] = run; run += v1;
  if (base + 2 < n) offs[base + 2] = run; run += v2;
  if (base + 3 < n) offs[base + 3] = run; run += v3;
  #pragma unroll
  for (int u = 0; u < 4; ++u){
    int i = base + u;
    if (i < n){
      float d = (float)((u == 0) ? v0 : (u == 1) ? v1 : (u == 2) ? v2 : v3);
      dis[i]  = rsqrtf(d + 1.0f);       // GCN: deg includes self-loop
      invd[i] = 1.0f / fmaxf(d, 1.0f);  // SAGE mean divisor
    }
  }
}

// ---------------- fp32 -> fp16 convert (layer-1 gather of x) ---------------

__global__ __launch_bounds__(256) void k_f2h(const float* __restrict__ in,
                                             ushort* __restrict__ out, int n4){
  int i = blockIdx.x * 256 + threadIdx.x;
  if (i < n4){
    float4 v = ((const float4*)in)[i];
    ((ushort4*)out)[i] = pack_h4(v);
  }
}

// ---------------- Aggregation: quarter-wave fp16 gather --------------------

template<int MODE>
__global__ __launch_bounds__(256) void k_agg(const ushort* __restrict__ in,
                                             const int* __restrict__ offs,
                                             const int* __restrict__ csr,
                                             const float* __restrict__ dis,
                                             const float* __restrict__ invd,
                                             float* __restrict__ out, int n){
  int node = (blockIdx.x * 256 + threadIdx.x) >> 6;
  if (node >= n) return;
  int lane = threadIdx.x & 63;
  int g    = lane >> 4;          // neighbor sub-group 0..3
  int fl   = (lane & 15) * 4;    // feature chunk
  int s = offs[node], e = offs[node + 1];

  float4 acc = make_float4(0.f, 0.f, 0.f, 0.f);
  #pragma unroll 4
  for (int k = s + g; k < e; k += 4){
    int j = csr[k];
    float4 v = unpack_h4(*(const ushort4*)(in + (size_t)j * 64 + fl));
    if (MODE == 0){
      fma4(acc, dis[j], v);
    } else {
      acc.x += v.x; acc.y += v.y; acc.z += v.z; acc.w += v.w;
    }
  }

  acc.x += __shfl_xor(acc.x, 16); acc.y += __shfl_xor(acc.y, 16);
  acc.z += __shfl_xor(acc.z, 16); acc.w += __shfl_xor(acc.w, 16);
  acc.x += __shfl_xor(acc.x, 32); acc.y += __shfl_xor(acc.y, 32);
  acc.z += __shfl_xor(acc.z, 32); acc.w += __shfl_xor(acc.w, 32);

  if (g == 0){
    float4 r;
    if (MODE == 0){
      float di = dis[node];
      float4 self = unpack_h4(*(const ushort4*)(in + (size_t)node * 64 + fl));
      float d2 = di * di;
      r.x = di * acc.x + d2 * self.x;
      r.y = di * acc.y + d2 * self.y;
      r.z = di * acc.z + d2 * self.z;
      r.w = di * acc.w + d2 * self.w;
    } else {
      float iv = invd[node];
      r.x = acc.x * iv; r.y = acc.y * iv; r.z = acc.z * iv; r.w = acc.w * iv;
    }
    *(float4*)(out + (size_t)node * 64 + fl) = r;
  }
}

// ---------------- Dense 64x64 GEMM tiles ----------------

__device__ __forceinline__ void stage_A(const float* __restrict__ A,
                                        float (*As)[68], int row0, int n, int t){
  #pragma unroll
  for (int u = 0; u < 4; ++u){
    int q = u * 256 + t;
    int r = q >> 4;
    int c = (q & 15) * 4;
    int gr = row0 + r;
    float4 v = make_float4(0.f, 0.f, 0.f, 0.f);
    if (gr < n) v = *(const float4*)(A + (size_t)gr * 64 + c);
    *(float4*)&As[r][c] = v;
  }
}

__device__ __forceinline__ void stage_W(const float* __restrict__ W,
                                        float (*Ws)[64], int t){
  #pragma unroll
  for (int u = 0; u < 4; ++u){
    int q = u * 256 + t;
    int r = q >> 4;
    int c = (q & 15) * 4;
    *(float4*)&Ws[r][c] = *(const float4*)(W + r * 64 + c);
  }
}

__device__ __forceinline__ void tile_mm(const float (*As)[68], const float (*Ws)[64],
                                        float4 acc[4], int r0, int c0){
  #pragma unroll 2
  for (int k0 = 0; k0 < 64; k0 += 4){
    float4 a0 = *(const float4*)&As[r0+0][k0];
    float4 a1 = *(const float4*)&As[r0+1][k0];
    float4 a2 = *(const float4*)&As[r0+2][k0];
    float4 a3 = *(const float4*)&As[r0+3][k0];
    float4 w0 = *(const float4*)&Ws[k0+0][c0];
    float4 w1 = *(const float4*)&Ws[k0+1][c0];
    float4 w2 = *(const float4*)&Ws[k0+2][c0];
    float4 w3 = *(const float4*)&Ws[k0+3][c0];
    fma4(acc[0], a0.x, w0); fma4(acc[0], a0.y, w1); fma4(acc[0], a0.z, w2); fma4(acc[0], a0.w, w3);
    fma4(acc[1], a1.x, w0); fma4(acc[1], a1.y, w1); fma4(acc[1], a1.z, w2); fma4(acc[1], a1.w, w3);
    fma4(acc[2], a2.x, w0); fma4(acc[2], a2.y, w1); fma4(acc[2], a2.z, w2); fma4(acc[2], a2.w, w3);
    fma4(acc[3], a3.x, w0); fma4(acc[3], a3.y, w1); fma4(acc[3], a3.z, w2); fma4(acc[3], a3.w, w3);
  }
}

// out = act(A @ W + bias)  [+ fp16 mirror if outh != nullptr]
template<bool RELU>
__global__ __launch_bounds__(256, 2) void k_gemm1(const float* __restrict__ A,
                                                  const float* __restrict__ W,
                                                  const float* __restrict__ bias,
                                                  float* __restrict__ out,
                                                  ushort* __restrict__ outh, int n){
  __shared__ __align__(16) float As[64][68];
  __shared__ __align__(16) float Ws[64][64];
  int t = threadIdx.x;
  int row0 = blockIdx.x * 64;
  stage_W(W, Ws, t);
  stage_A(A, As, row0, n, t);
  __syncthreads();
  int r0 = (t >> 4) * 4, c0 = (t & 15) * 4;
  float4 b4 = *(const float4*)(bias + c0);
  float4 acc[4] = {b4, b4, b4, b4};
  tile_mm(As, Ws, acc, r0, c0);
  #pragma unroll
  for (int i = 0; i < 4; ++i){
    int gr = row0 + r0 + i;
    if (gr < n){
      float4 v = acc[i];
      if (RELU){
        v.x = fmaxf(v.x, 0.f); v.y = fmaxf(v.y, 0.f);
        v.z = fmaxf(v.z, 0.f); v.w = fmaxf(v.w, 0.f);
      }
      *(float4*)(out + (size_t)gr * 64 + c0) = v;
      if (outh) *(ushort4*)(outh + (size_t)gr * 64 + c0) = pack_h4(v);
    }
  }
}

// out = act(A @ W1 + B @ W2 + bias + B)   (SAGE layer with residual)
template<bool RELU>
__global__ __launch_bounds__(256, 2) void k_gemm_dual(const float* __restrict__ A,
                                                      const float* __restrict__ B,
                                                      const float* __restrict__ W1,
                                                      const float* __restrict__ W2,
                                                      const float* __restrict__ bias,
                                                      float* __restrict__ out,
                                                      ushort* __restrict__ outh, int n){
  __shared__ __align__(16) float As[64][68];
  __shared__ __align__(16) float Ws1[64][64];
  __shared__ __align__(16) float Ws2[64][64];
  int t = threadIdx.x;
  int row0 = blockIdx.x * 64;
  stage_W(W1, Ws1, t);
  stage_W(W2, Ws2, t);
  stage_A(A, As, row0, n, t);
  __syncthreads();
  int r0 = (t >> 4) * 4, c0 = (t & 15) * 4;
  float4 b4 = *(const float4*)(bias + c0);
  float4 acc[4] = {b4, b4, b4, b4};
  tile_mm(As, Ws1, acc, r0, c0);
  __syncthreads();
  stage_A(B, As, row0, n, t);
  __syncthreads();
  tile_mm(As, Ws2, acc, r0, c0);
  #pragma unroll
  for (int i = 0; i < 4; ++i){
    float4 res = *(const float4*)&As[r0 + i][c0];   // B tile still in LDS
    acc[i].x += res.x; acc[i].y += res.y; acc[i].z += res.z; acc[i].w += res.w;
    if (RELU){
      acc[i].x = fmaxf(acc[i].x, 0.f); acc[i].y = fmaxf(acc[i].y, 0.f);
      acc[i].z = fmaxf(acc[i].z, 0.f); acc[i].w = fmaxf(acc[i].w, 0.f);
    }
    int gr = row0 + r0 + i;
    if (gr < n){
      *(float4*)(out + (size_t)gr * 64 + c0) = acc[i];
      if (outh) *(ushort4*)(outh + (size_t)gr * 64 + c0) = pack_h4(acc[i]);
    }
  }
}

// out = relu((A@W1 + B@W2 + b12 + B) @ W3 + b3)   (SAGE+res fused with lin)
template<bool RELU>
__global__ __launch_bounds__(256, 2) void k_gemm_tri(const float* __restrict__ A,
                                                     const float* __restrict__ B,
                                                     const float* __restrict__ W1,
                                                     const float* __restrict__ W2,
                                                     const float* __restrict__ b12,
                                                     const float* __restrict__ W3,
                                                     const float* __restrict__ b3,
                                                     float* __restrict__ out,
                                                     ushort* __restrict__ outh, int n){
  __shared__ __align__(16) float As[64][68];
  __shared__ __align__(16) float Ws1[64][64];
  __shared__ __align__(16) float Ws2[64][64];
  int t = threadIdx.x;
  int row0 = blockIdx.x * 64;
  stage_W(W1, Ws1, t);
  stage_W(W2, Ws2, t);
  stage_A(A, As, row0, n, t);
  __syncthreads();
  int r0 = (t >> 4) * 4, c0 = (t & 15) * 4;
  float4 b4 = *(const float4*)(b12 + c0);
  float4 acc[4] = {b4, b4, b4, b4};
  tile_mm(As, Ws1, acc, r0, c0);
  __syncthreads();
  stage_A(B, As, row0, n, t);
  __syncthreads();
  tile_mm(As, Ws2, acc, r0, c0);
  #pragma unroll
  for (int i = 0; i < 4; ++i){
    float4 res = *(const float4*)&As[r0 + i][c0];   // +B residual
    acc[i].x += res.x; acc[i].y += res.y; acc[i].z += res.z; acc[i].w += res.w;
  }
  __syncthreads();                     // done reading As(B) and Ws1
  // t3 tile -> As; stage W3 over Ws1
  #pragma unroll
  for (int i = 0; i < 4; ++i) *(float4*)&As[r0 + i][c0] = acc[i];
  stage_W(W3, Ws1, t);
  __syncthreads();
  float4 bb = *(const float4*)(b3 + c0);
  float4 acc2[4] = {bb, bb, bb, bb};
  tile_mm(As, Ws1, acc2, r0, c0);
  #pragma unroll
  for (int i = 0; i < 4; ++i){
    float4 v = acc2[i];
    if (RELU){
      v.x = fmaxf(v.x, 0.f); v.y = fmaxf(v.y, 0.f);
      v.z = fmaxf(v.z, 0.f); v.w = fmaxf(v.w, 0.f);
    }
    int gr = row0 + r0 + i;
    if (gr < n){
      *(float4*)(out + (size_t)gr * 64 + c0) = v;
      if (outh) *(ushort4*)(outh + (size_t)gr * 64 + c0) = pack_h4(v);
    }
  }
}

// ---------------------------------------------------------------------------

extern "C" void kernel_launch(void* const* d_in, const int* in_sizes, int n_in,
                              void* d_out, int out_size, void* d_ws, size_t ws_size,
                              hipStream_t stream){
  const float* x        = (const float*)d_in[0];
  const int*   ei       = (const int*)  d_in[1];
  const float* gcn1_w   = (const float*)d_in[2];
  const float* gcn1_b   = (const float*)d_in[3];
  const float* sage1_lw = (const float*)d_in[4];
  const float* sage1_lb = (const float*)d_in[5];
  const float* sage1_rw = (const float*)d_in[6];
  const float* sage2_lw = (const float*)d_in[7];
  const float* sage2_lb = (const float*)d_in[8];
  const float* sage2_rw = (const float*)d_in[9];
  const float* lin_w    = (const float*)d_in[10];
  const float* lin_b    = (const float*)d_in[11];
  const float* gcn2_w   = (const float*)d_in[12];
  const float* gcn2_b   = (const float*)d_in[13];
  float* out = (float*)d_out;

  const int n = in_sizes[0] / 64;
  const int E = in_sizes[1] / 2;
  const int* src = ei;
  const int* dst = ei + E;
  const int SL  = (n + NSL - 1) / NSL;   // dst-slice width
  const int cap = E / 4;                 // per-slice bucket capacity (~2x expected)

  // workspace carve (~70 MB); bkt aliases bufA (dead during CSR build)
  uintptr_t p = (uintptr_t)d_ws;
  auto alloc = [&](size_t b) -> void* {
    p = (p + 255) & ~(uintptr_t)255;
    void* r = (void*)p; p += b; return r;
  };
  float*  bufA = (float*)alloc((size_t)n * 64 * 4);
  float*  bufB = (float*)alloc((size_t)n * 64 * 4);
  ushort* hh   = (ushort*)alloc((size_t)n * 64 * 2);  // fp16 gather mirror
  int*    deg  = (int*)  alloc((size_t)(n + 24) * 4); // + bcnt(8) + work0(8) + work1(8)
  int*    bcnt  = deg + n;
  int*    work0 = deg + n + 8;
  int*    work1 = deg + n + 16;
  int*    offs = (int*)  alloc((size_t)(n + 1) * 4);
  const int NB = (n + 1023) / 1024;
  int*    bsum  = (int*) alloc((size_t)NB * 4);
  int*    bscan = (int*) alloc((size_t)NB * 4);
  int*    csr   = (int*) alloc((size_t)E * 4);
  float*  dis   = (float*)alloc((size_t)n * 4);
  float*  invd  = (float*)alloc((size_t)n * 4);
  ull*    bkt   = (ull*)bufA;            // 8 * cap * 8B = 20 MB < bufA (25.6 MB)

  hipMemsetAsync(deg, 0, (size_t)(n + 24) * 4, stream);

  const int gAgg = (n + 3) / 4;      // one wave per node, 4 waves/block
  const int gG = (n + 63) / 64;      // 64-row GEMM tiles
  const int gC = (n * 16 + 255) / 256;

  // CSR build: bucket scatter -> XCD-affine deg -> scan(+prep) -> XCD-affine fill
  k_bucket<<<BKT_BLOCKS, 256, 0, stream>>>(src, dst, bkt, bcnt, E, SL, cap);
  k_deg2  <<<SLICE_BLOCKS, 256, 0, stream>>>(bkt, bcnt, work0, deg, cap);
  k_scanA <<<NB, 256, 0, stream>>>(deg, bsum, n);
  k_scanB <<<1, 1, 0, stream>>>(bsum, bscan, offs, NB, n);
  k_scanC <<<NB, 256, 0, stream>>>(deg, bscan, offs, dis, invd, n);
  k_fill2 <<<SLICE_BLOCKS, 256, 0, stream>>>(bkt, bcnt, offs, work1, deg, csr, cap);

  // Layer 1: h1 = relu(GCNagg(x) @ gcn1_w + b)           -> d_out (+hh)
  k_f2h<<<gC, 256, 0, stream>>>(x, hh, n * 16);
  k_agg<0><<<gAgg, 256, 0, stream>>>(hh, offs, csr, dis, invd, bufA, n);
  k_gemm1<true><<<gG, 256, 0, stream>>>(bufA, gcn1_w, gcn1_b, out, hh, n);

  // Layer 2: h2 = relu(mean(h1)@Wl + bl + h1@Wr + h1)    -> bufB (+hh)
  k_agg<1><<<gAgg, 256, 0, stream>>>(hh, offs, csr, dis, invd, bufA, n);
  k_gemm_dual<true><<<gG, 256, 0, stream>>>(bufA, out, sage1_lw, sage1_rw, sage1_lb, bufB, hh, n);

  // Layer 3 (fused 3a+3b): h4 = relu((mean(h2)@Wl2+bl2+h2@Wr2+h2)@lin_w+lin_b)
  //                                                      -> bufB (+hh), in-place safe per-block
  k_agg<1><<<gAgg, 256, 0, stream>>>(hh, offs, csr, dis, invd, bufA, n);
  k_gemm_tri<true><<<gG, 256, 0, stream>>>(bufA, bufB, sage2_lw, sage2_rw, sage2_lb,
                                           lin_w, lin_b, bufB, hh, n);

  // Layer 4: out = GCNagg(h4) @ gcn2_w + gcn2_b          -> d_out
  k_agg<0><<<gAgg, 256, 0, stream>>>(hh, offs, csr, dis, invd, bufA, n);
  k_gemm1<false><<<gG, 256, 0, stream>>>(bufA, gcn2_w, gcn2_b, out, (ushort*)nullptr, n);
}

// Round 7
// 500.837 us; speedup vs baseline: 1.3525x; 1.3525x over previous
//
#include <hip/hip_runtime.h>
#include <hip/hip_fp16.h>
#include <stdint.h>

// ---------------------------------------------------------------------------
// GNN forward: GCN -> SAGE(+res) -> SAGE(+res) -> lin -> GCN
// Strategy: aggregate-first (linearity), CSR built once per call, fused dense
// 64x64 GEMM epilogues, fp16 gather mirror.
// R2: bounded unroll + launch_bounds(256,2) fixed GEMM spill.
// R3/R4: quarter-wave gather, fp16 mirror.
// R5: counting-sort bucket scatter (edges read 2x).
// R6: work-steal XCD affinity REGRESSED (atomic cursor + syncthreads serialized
//     fill; WRITE_SIZE never moved -> it's L3-absorbed L2 writeback, not a
//     real cost). Lesson: minimize passes/atomics, ignore WRITE_SIZE here.
// R7: revert fill to R5 form; DELETE k_deg2 (deg counting fused into k_bucket
//     pass 1 which already streams dst); k_agg widened to 8x8-lane groups with
//     16B ushort8 loads (half the vmem instrs, 8 rows/round).
// ---------------------------------------------------------------------------

typedef unsigned long long ull;
typedef unsigned short ushort8v __attribute__((ext_vector_type(8)));

#define NSL 8
#define BKT_BLOCKS 512

__device__ __forceinline__ void fma4(float4& a, float s, const float4& w){
  a.x = fmaf(s, w.x, a.x);
  a.y = fmaf(s, w.y, a.y);
  a.z = fmaf(s, w.z, a.z);
  a.w = fmaf(s, w.w, a.w);
}

__device__ __forceinline__ ushort4 pack_h4(float4 v){
  ushort4 u;
  u.x = __half_as_ushort(__float2half(v.x));
  u.y = __half_as_ushort(__float2half(v.y));
  u.z = __half_as_ushort(__float2half(v.z));
  u.w = __half_as_ushort(__float2half(v.w));
  return u;
}

// ---------------- CSR build: bucket scatter (+deg fused) ----------------
// 8 slices by dst. Pass 1: LDS histogram + global deg count (fire-and-forget
// atomics on data we're already streaming). One reservation per slice per
// block. Pass 2: scatter packed (src<<32|dst) into per-slice buckets.

__global__ __launch_bounds__(256) void k_bucket(const int* __restrict__ src,
                                                const int* __restrict__ dst,
                                                ull* __restrict__ bkt,
                                                int* __restrict__ bcnt,
                                                int* __restrict__ deg,
                                                int E, int SL, int cap){
  __shared__ int hist[NSL];
  __shared__ int cur[NSL];
  int t = threadIdx.x;
  int chunk = (E + BKT_BLOCKS - 1) / BKT_BLOCKS;
  int e0 = blockIdx.x * chunk;
  int e1 = min(E, e0 + chunk);
  if (t < NSL) hist[t] = 0;
  __syncthreads();
  for (int e = e0 + t; e < e1; e += 256){
    int d = dst[e];
    atomicAdd(&deg[d], 1);          // fused degree count (no return needed)
    atomicAdd(&hist[d / SL], 1);
  }
  __syncthreads();
  if (t < NSL){
    int h = hist[t];
    cur[t] = h ? atomicAdd(&bcnt[t], h) : 0;
  }
  __syncthreads();
  for (int e = e0 + t; e < e1; e += 256){   // chunk re-read is L2-hot
    int d = dst[e];
    int s = d / SL;
    int pos = atomicAdd(&cur[s], 1);
    if (pos < cap)
      bkt[(size_t)s * cap + pos] = ((ull)(unsigned)src[e] << 32) | (unsigned)d;
  }
}

// slice-strided fill (R5 form): deg counts down to 0; csr lines slice-local
__global__ __launch_bounds__(256) void k_fill2(const ull* __restrict__ bkt,
                                               const int* __restrict__ bcnt,
                                               const int* __restrict__ offs,
                                               int* __restrict__ deg,
                                               int* __restrict__ csr, int cap){
  int s = blockIdx.x & 7;
  int q = blockIdx.x >> 3;
  int cnt = min(bcnt[s], cap);
  const ull* b = bkt + (size_t)s * cap;
  for (int i = q * 256 + threadIdx.x; i < cnt; i += (1024 / 8) * 256){
    ull pk = b[i];
    int d  = (int)(pk & 0xffffffffu);
    int sr = (int)(pk >> 32);
    int p  = offs[d] + atomicSub(&deg[d], 1) - 1;
    csr[p] = sr;
  }
}

// ---------------- scans (+prep fused into scanC) ----------------

__global__ __launch_bounds__(256) void k_scanA(const int* __restrict__ deg,
                                               int* __restrict__ bsum, int n){
  __shared__ int sm[256];
  int b = blockIdx.x, t = threadIdx.x;
  int base = b * 1024 + t * 4;
  int s = 0;
  #pragma unroll
  for (int u = 0; u < 4; ++u){ int i = base + u; if (i < n) s += deg[i]; }
  sm[t] = s; __syncthreads();
  for (int off = 128; off > 0; off >>= 1){
    if (t < off) sm[t] += sm[t + off];
    __syncthreads();
  }
  if (t == 0) bsum[b] = sm[0];
}

__global__ void k_scanB(const int* __restrict__ bsum, int* __restrict__ bscan,
                        int* __restrict__ offs, int nb, int n){
  if (blockIdx.x == 0 && threadIdx.x == 0){
    int run = 0;
    for (int i = 0; i < nb; ++i){ bscan[i] = run; run += bsum[i]; }
    offs[n] = run;
  }
}

__global__ __launch_bounds__(256) void k_scanC(const int* __restrict__ deg,
                                               const int* __restrict__ bscan,
                                               int* __restrict__ offs,
                                               float* __restrict__ dis,
                                               float* __restrict__ invd, int n){
  __shared__ int sm[256];
  int b = blockIdx.x, t = threadIdx.x;
  int base = b * 1024 + t * 4;
  int v0 = (base + 0 < n) ? deg[base + 0] : 0;
  int v1 = (base + 1 < n) ? deg[base + 1] : 0;
  int v2 = (base + 2 < n) ? deg[base + 2] : 0;
  int v3 = (base + 3 < n) ? deg[base + 3] : 0;
  int ts = v0 + v1 + v2 + v3;
  sm[t] = ts; __syncthreads();
  #pragma unroll
  for (int off = 1; off < 256; off <<= 1){
    int add = (t >= off) ? sm[t - off] : 0;
    __syncthreads();
    sm[t] += add;
    __syncthreads();
  }
  int excl = sm[t] - ts;
  int run = bscan[b] + excl;
  if (base + 0 < n) offs[base + 0] = run; run += v0;
  if (base + 1 < n) offs[base + 1] = run; run += v1;
  if (base + 2 < n) offs[base + 2] = run; run += v2;
  if (base + 3 < n) offs[base + 3] = run; run += v3;
  #pragma unroll
  for (int u = 0; u < 4; ++u){
    int i = base + u;
    if (i < n){
      float d = (float)((u == 0) ? v0 : (u == 1) ? v1 : (u == 2) ? v2 : v3);
      dis[i]  = rsqrtf(d + 1.0f);       // GCN: deg includes self-loop
      invd[i] = 1.0f / fmaxf(d, 1.0f);  // SAGE mean divisor
    }
  }
}

// ---------------- fp32 -> fp16 convert (layer-1 gather of x) ---------------

__global__ __launch_bounds__(256) void k_f2h(const float* __restrict__ in,
                                             ushort* __restrict__ out, int n4){
  int i = blockIdx.x * 256 + threadIdx.x;
  if (i < n4){
    float4 v = ((const float4*)in)[i];
    ushort4 u = pack_h4(v);
    ((ushort4*)out)[i] = u;
  }
}

// ---------------- Aggregation: 8x8-lane fp16 gather --------------------
// One wave per node. Lane l: group g=l>>3 handles neighbor csr[k+g], features
// (l&7)*8..+7 as ushort8 (16B dwordx4). One round = 8 rows; unroll 2 -> 16
// rows (32 lines) in flight per wave. Reduce: shfl_xor 8/16/32.
// MODE 0: GCN  out[i] = dis[i]*sum_j dis[j]*in[j] + dis[i]^2*in[i]
// MODE 1: SAGE out[i] = (sum_j in[j]) / max(deg,1)

template<int MODE>
__global__ __launch_bounds__(256) void k_agg(const ushort* __restrict__ in,
                                             const int* __restrict__ offs,
                                             const int* __restrict__ csr,
                                             const float* __restrict__ dis,
                                             const float* __restrict__ invd,
                                             float* __restrict__ out, int n){
  int node = (blockIdx.x * 256 + threadIdx.x) >> 6;
  if (node >= n) return;
  int lane = threadIdx.x & 63;
  int g    = lane >> 3;          // neighbor sub-group 0..7
  int fl   = (lane & 7) * 8;     // feature chunk of 8
  int s = offs[node], e = offs[node + 1];

  float acc[8] = {0.f, 0.f, 0.f, 0.f, 0.f, 0.f, 0.f, 0.f};
  #pragma unroll 2
  for (int k = s + g; k < e; k += 8){
    int j = csr[k];
    ushort8v v = *(const ushort8v*)(in + (size_t)j * 64 + fl);
    float w = (MODE == 0) ? dis[j] : 1.0f;
    #pragma unroll
    for (int q = 0; q < 8; ++q)
      acc[q] = fmaf(w, __half2float(__ushort_as_half(v[q])), acc[q]);
  }

  // combine the 8 neighbor-groups
  #pragma unroll
  for (int q = 0; q < 8; ++q) acc[q] += __shfl_xor(acc[q], 8);
  #pragma unroll
  for (int q = 0; q < 8; ++q) acc[q] += __shfl_xor(acc[q], 16);
  #pragma unroll
  for (int q = 0; q < 8; ++q) acc[q] += __shfl_xor(acc[q], 32);

  if (g == 0){
    float r[8];
    if (MODE == 0){
      float di = dis[node];
      float d2 = di * di;
      ushort8v self = *(const ushort8v*)(in + (size_t)node * 64 + fl);
      #pragma unroll
      for (int q = 0; q < 8; ++q)
        r[q] = di * acc[q] + d2 * __half2float(__ushort_as_half(self[q]));
    } else {
      float iv = invd[node];
      #pragma unroll
      for (int q = 0; q < 8; ++q) r[q] = acc[q] * iv;
    }
    float* o = out + (size_t)node * 64 + fl;
    *(float4*)(o + 0) = make_float4(r[0], r[1], r[2], r[3]);
    *(float4*)(o + 4) = make_float4(r[4], r[5], r[6], r[7]);
  }
}

// ---------------- Dense 64x64 GEMM tiles ----------------

__device__ __forceinline__ void stage_A(const float* __restrict__ A,
                                        float (*As)[68], int row0, int n, int t){
  #pragma unroll
  for (int u = 0; u < 4; ++u){
    int q = u * 256 + t;
    int r = q >> 4;
    int c = (q & 15) * 4;
    int gr = row0 + r;
    float4 v = make_float4(0.f, 0.f, 0.f, 0.f);
    if (gr < n) v = *(const float4*)(A + (size_t)gr * 64 + c);
    *(float4*)&As[r][c] = v;
  }
}

__device__ __forceinline__ void stage_W(const float* __restrict__ W,
                                        float (*Ws)[64], int t){
  #pragma unroll
  for (int u = 0; u < 4; ++u){
    int q = u * 256 + t;
    int r = q >> 4;
    int c = (q & 15) * 4;
    *(float4*)&Ws[r][c] = *(const float4*)(W + r * 64 + c);
  }
}

__device__ __forceinline__ void tile_mm(const float (*As)[68], const float (*Ws)[64],
                                        float4 acc[4], int r0, int c0){
  #pragma unroll 2
  for (int k0 = 0; k0 < 64; k0 += 4){
    float4 a0 = *(const float4*)&As[r0+0][k0];
    float4 a1 = *(const float4*)&As[r0+1][k0];
    float4 a2 = *(const float4*)&As[r0+2][k0];
    float4 a3 = *(const float4*)&As[r0+3][k0];
    float4 w0 = *(const float4*)&Ws[k0+0][c0];
    float4 w1 = *(const float4*)&Ws[k0+1][c0];
    float4 w2 = *(const float4*)&Ws[k0+2][c0];
    float4 w3 = *(const float4*)&Ws[k0+3][c0];
    fma4(acc[0], a0.x, w0); fma4(acc[0], a0.y, w1); fma4(acc[0], a0.z, w2); fma4(acc[0], a0.w, w3);
    fma4(acc[1], a1.x, w0); fma4(acc[1], a1.y, w1); fma4(acc[1], a1.z, w2); fma4(acc[1], a1.w, w3);
    fma4(acc[2], a2.x, w0); fma4(acc[2], a2.y, w1); fma4(acc[2], a2.z, w2); fma4(acc[2], a2.w, w3);
    fma4(acc[3], a3.x, w0); fma4(acc[3], a3.y, w1); fma4(acc[3], a3.z, w2); fma4(acc[3], a3.w, w3);
  }
}

// out = act(A @ W + bias)  [+ fp16 mirror if outh != nullptr]
template<bool RELU>
__global__ __launch_bounds__(256, 2) void k_gemm1(const float* __restrict__ A,
                                                  const float* __restrict__ W,
                                                  const float* __restrict__ bias,
                                                  float* __restrict__ out,
                                                  ushort* __restrict__ outh, int n){
  __shared__ __align__(16) float As[64][68];
  __shared__ __align__(16) float Ws[64][64];
  int t = threadIdx.x;
  int row0 = blockIdx.x * 64;
  stage_W(W, Ws, t);
  stage_A(A, As, row0, n, t);
  __syncthreads();
  int r0 = (t >> 4) * 4, c0 = (t & 15) * 4;
  float4 b4 = *(const float4*)(bias + c0);
  float4 acc[4] = {b4, b4, b4, b4};
  tile_mm(As, Ws, acc, r0, c0);
  #pragma unroll
  for (int i = 0; i < 4; ++i){
    int gr = row0 + r0 + i;
    if (gr < n){
      float4 v = acc[i];
      if (RELU){
        v.x = fmaxf(v.x, 0.f); v.y = fmaxf(v.y, 0.f);
        v.z = fmaxf(v.z, 0.f); v.w = fmaxf(v.w, 0.f);
      }
      *(float4*)(out + (size_t)gr * 64 + c0) = v;
      if (outh) *(ushort4*)(outh + (size_t)gr * 64 + c0) = pack_h4(v);
    }
  }
}

// out = act(A @ W1 + B @ W2 + bias + B)   (SAGE layer with residual)
template<bool RELU>
__global__ __launch_bounds__(256, 2) void k_gemm_dual(const float* __restrict__ A,
                                                      const float* __restrict__ B,
                                                      const float* __restrict__ W1,
                                                      const float* __restrict__ W2,
                                                      const float* __restrict__ bias,
                                                      float* __restrict__ out,
                                                      ushort* __restrict__ outh, int n){
  __shared__ __align__(16) float As[64][68];
  __shared__ __align__(16) float Ws1[64][64];
  __shared__ __align__(16) float Ws2[64][64];
  int t = threadIdx.x;
  int row0 = blockIdx.x * 64;
  stage_W(W1, Ws1, t);
  stage_W(W2, Ws2, t);
  stage_A(A, As, row0, n, t);
  __syncthreads();
  int r0 = (t >> 4) * 4, c0 = (t & 15) * 4;
  float4 b4 = *(const float4*)(bias + c0);
  float4 acc[4] = {b4, b4, b4, b4};
  tile_mm(As, Ws1, acc, r0, c0);
  __syncthreads();
  stage_A(B, As, row0, n, t);
  __syncthreads();
  tile_mm(As, Ws2, acc, r0, c0);
  #pragma unroll
  for (int i = 0; i < 4; ++i){
    float4 res = *(const float4*)&As[r0 + i][c0];   // B tile still in LDS
    acc[i].x += res.x; acc[i].y += res.y; acc[i].z += res.z; acc[i].w += res.w;
    if (RELU){
      acc[i].x = fmaxf(acc[i].x, 0.f); acc[i].y = fmaxf(acc[i].y, 0.f);
      acc[i].z = fmaxf(acc[i].z, 0.f); acc[i].w = fmaxf(acc[i].w, 0.f);
    }
    int gr = row0 + r0 + i;
    if (gr < n){
      *(float4*)(out + (size_t)gr * 64 + c0) = acc[i];
      if (outh) *(ushort4*)(outh + (size_t)gr * 64 + c0) = pack_h4(acc[i]);
    }
  }
}

// out = relu((A@W1 + B@W2 + b12 + B) @ W3 + b3)   (SAGE+res fused with lin)
template<bool RELU>
__global__ __launch_bounds__(256, 2) void k_gemm_tri(const float* __restrict__ A,
                                                     const float* __restrict__ B,
                                                     const float* __restrict__ W1,
                                                     const float* __restrict__ W2,
                                                     const float* __restrict__ b12,
                                                     const float* __restrict__ W3,
                                                     const float* __restrict__ b3,
                                                     float* __restrict__ out,
                                                     ushort* __restrict__ outh, int n){
  __shared__ __align__(16) float As[64][68];
  __shared__ __align__(16) float Ws1[64][64];
  __shared__ __align__(16) float Ws2[64][64];
  int t = threadIdx.x;
  int row0 = blockIdx.x * 64;
  stage_W(W1, Ws1, t);
  stage_W(W2, Ws2, t);
  stage_A(A, As, row0, n, t);
  __syncthreads();
  int r0 = (t >> 4) * 4, c0 = (t & 15) * 4;
  float4 b4 = *(const float4*)(b12 + c0);
  float4 acc[4] = {b4, b4, b4, b4};
  tile_mm(As, Ws1, acc, r0, c0);
  __syncthreads();
  stage_A(B, As, row0, n, t);
  __syncthreads();
  tile_mm(As, Ws2, acc, r0, c0);
  #pragma unroll
  for (int i = 0; i < 4; ++i){
    float4 res = *(const float4*)&As[r0 + i][c0];   // +B residual
    acc[i].x += res.x; acc[i].y += res.y; acc[i].z += res.z; acc[i].w += res.w;
  }
  __syncthreads();                     // done reading As(B) and Ws1
  #pragma unroll
  for (int i = 0; i < 4; ++i) *(float4*)&As[r0 + i][c0] = acc[i];
  stage_W(W3, Ws1, t);
  __syncthreads();
  float4 bb = *(const float4*)(b3 + c0);
  float4 acc2[4] = {bb, bb, bb, bb};
  tile_mm(As, Ws1, acc2, r0, c0);
  #pragma unroll
  for (int i = 0; i < 4; ++i){
    float4 v = acc2[i];
    if (RELU){
      v.x = fmaxf(v.x, 0.f); v.y = fmaxf(v.y, 0.f);
      v.z = fmaxf(v.z, 0.f); v.w = fmaxf(v.w, 0.f);
    }
    int gr = row0 + r0 + i;
    if (gr < n){
      *(float4*)(out + (size_t)gr * 64 + c0) = v;
      if (outh) *(ushort4*)(outh + (size_t)gr * 64 + c0) = pack_h4(v);
    }
  }
}

// ---------------------------------------------------------------------------

extern "C" void kernel_launch(void* const* d_in, const int* in_sizes, int n_in,
                              void* d_out, int out_size, void* d_ws, size_t ws_size,
                              hipStream_t stream){
  const float* x        = (const float*)d_in[0];
  const int*   ei       = (const int*)  d_in[1];
  const float* gcn1_w   = (const float*)d_in[2];
  const float* gcn1_b   = (const float*)d_in[3];
  const float* sage1_lw = (const float*)d_in[4];
  const float* sage1_lb = (const float*)d_in[5];
  const float* sage1_rw = (const float*)d_in[6];
  const float* sage2_lw = (const float*)d_in[7];
  const float* sage2_lb = (const float*)d_in[8];
  const float* sage2_rw = (const float*)d_in[9];
  const float* lin_w    = (const float*)d_in[10];
  const float* lin_b    = (const float*)d_in[11];
  const float* gcn2_w   = (const float*)d_in[12];
  const float* gcn2_b   = (const float*)d_in[13];
  float* out = (float*)d_out;

  const int n = in_sizes[0] / 64;
  const int E = in_sizes[1] / 2;
  const int* src = ei;
  const int* dst = ei + E;
  const int SL  = (n + NSL - 1) / NSL;   // dst-slice width
  const int cap = E / 4;                 // per-slice bucket capacity (~2x expected)

  // workspace carve (~70 MB); bkt aliases bufA (dead during CSR build)
  uintptr_t p = (uintptr_t)d_ws;
  auto alloc = [&](size_t b) -> void* {
    p = (p + 255) & ~(uintptr_t)255;
    void* r = (void*)p; p += b; return r;
  };
  float*  bufA = (float*)alloc((size_t)n * 64 * 4);
  float*  bufB = (float*)alloc((size_t)n * 64 * 4);
  ushort* hh   = (ushort*)alloc((size_t)n * 64 * 2);  // fp16 gather mirror
  int*    deg  = (int*)  alloc((size_t)(n + 8) * 4);  // + bcnt(8) tail, one memset
  int*    bcnt = deg + n;
  int*    offs = (int*)  alloc((size_t)(n + 1) * 4);
  const int NB = (n + 1023) / 1024;
  int*    bsum  = (int*) alloc((size_t)NB * 4);
  int*    bscan = (int*) alloc((size_t)NB * 4);
  int*    csr   = (int*) alloc((size_t)E * 4);
  float*  dis   = (float*)alloc((size_t)n * 4);
  float*  invd  = (float*)alloc((size_t)n * 4);
  ull*    bkt   = (ull*)bufA;            // 8 * cap * 8B = 20 MB < bufA (25.6 MB)

  hipMemsetAsync(deg, 0, (size_t)(n + 8) * 4, stream);

  const int gAgg = (n + 3) / 4;      // one wave per node, 4 waves/block
  const int gG = (n + 63) / 64;      // 64-row GEMM tiles
  const int gC = (n * 16 + 255) / 256;

  // CSR build: bucket scatter(+deg) -> scan(+prep) -> slice-strided fill
  k_bucket<<<BKT_BLOCKS, 256, 0, stream>>>(src, dst, bkt, bcnt, deg, E, SL, cap);
  k_scanA <<<NB, 256, 0, stream>>>(deg, bsum, n);
  k_scanB <<<1, 1, 0, stream>>>(bsum, bscan, offs, NB, n);
  k_scanC <<<NB, 256, 0, stream>>>(deg, bscan, offs, dis, invd, n);
  k_fill2 <<<1024, 256, 0, stream>>>(bkt, bcnt, offs, deg, csr, cap);

  // Layer 1: h1 = relu(GCNagg(x) @ gcn1_w + b)           -> d_out (+hh)
  k_f2h<<<gC, 256, 0, stream>>>(x, hh, n * 16);
  k_agg<0><<<gAgg, 256, 0, stream>>>(hh, offs, csr, dis, invd, bufA, n);
  k_gemm1<true><<<gG, 256, 0, stream>>>(bufA, gcn1_w, gcn1_b, out, hh, n);

  // Layer 2: h2 = relu(mean(h1)@Wl + bl + h1@Wr + h1)    -> bufB (+hh)
  k_agg<1><<<gAgg, 256, 0, stream>>>(hh, offs, csr, dis, invd, bufA, n);
  k_gemm_dual<true><<<gG, 256, 0, stream>>>(bufA, out, sage1_lw, sage1_rw, sage1_lb, bufB, hh, n);

  // Layer 3 (fused 3a+3b): h4 = relu((mean(h2)@Wl2+bl2+h2@Wr2+h2)@lin_w+lin_b)
  //                                                      -> bufB (+hh), per-tile in-place safe
  k_agg<1><<<gAgg, 256, 0, stream>>>(hh, offs, csr, dis, invd, bufA, n);
  k_gemm_tri<true><<<gG, 256, 0, stream>>>(bufA, bufB, sage2_lw, sage2_rw, sage2_lb,
                                           lin_w, lin_b, bufB, hh, n);

  // Layer 4: out = GCNagg(h4) @ gcn2_w + gcn2_b          -> d_out
  k_agg<0><<<gAgg, 256, 0, stream>>>(hh, offs, csr, dis, invd, bufA, n);
  k_gemm1<false><<<gG, 256, 0, stream>>>(bufA, gcn2_w, gcn2_b, out, (ushort*)nullptr, n);
}

// Round 8
// 494.759 us; speedup vs baseline: 1.3691x; 1.0123x over previous
//
#include <hip/hip_runtime.h>
#include <hip/hip_fp16.h>
#include <stdint.h>

// ---------------------------------------------------------------------------
// GNN forward: GCN -> SAGE(+res) -> SAGE(+res) -> lin -> GCN
// Strategy: aggregate-first (linearity), CSR built once per call, fused dense
// 64x64 GEMM epilogues, fp16 gather mirror.
// R2: bounded unroll + launch_bounds(256,2) fixed GEMM spill.
// R3/R4: quarter-wave gather, fp16 mirror.  R5: bucket scatter.
// R6: work-steal regressed; WRITE_SIZE is L3-absorbed writeback, ignore it.
// R7: deg fused into bucket pass 1; 8x8-lane ushort8 gather.
// R8a: wave-aggregated bucket scatter (ballot group-by-slice, 1 LDS atomic per
//      slice-group per wave instead of 64 serialized lane atomics; R7 showed
//      472K LDS bank conflicts). BKT_BLOCKS 1024.
// R8b: k_fill2 2048 blocks (more MLP for the random atomicSub+scatter).
// R8c: dis-premultiplied fp16 mirror: hh = fp16(dis*x) -> GCN agg is a pure
//      sum + one final scale; kills the per-neighbor dis[j] gather.
// R8d: k_gemm_tri fp32 output was dead (layer 4 reads only hh) -> dropped.
// ---------------------------------------------------------------------------

typedef unsigned long long ull;
typedef unsigned short ushort8v __attribute__((ext_vector_type(8)));

#define NSL 8
#define BKT_BLOCKS 1024
#define FILL_BLOCKS 2048

__device__ __forceinline__ void fma4(float4& a, float s, const float4& w){
  a.x = fmaf(s, w.x, a.x);
  a.y = fmaf(s, w.y, a.y);
  a.z = fmaf(s, w.z, a.z);
  a.w = fmaf(s, w.w, a.w);
}

__device__ __forceinline__ ushort4 pack_h4(float4 v){
  ushort4 u;
  u.x = __half_as_ushort(__float2half(v.x));
  u.y = __half_as_ushort(__float2half(v.y));
  u.z = __half_as_ushort(__float2half(v.z));
  u.w = __half_as_ushort(__float2half(v.w));
  return u;
}

// ballot-group lanes of this wave by 3-bit slice id; returns mask of active
// lanes sharing this lane's slice.
__device__ __forceinline__ ull slice_group(bool act, int s){
  ull bm = __ballot(act);
  ull m0 = __ballot(s & 1);
  ull m1 = __ballot(s & 2);
  ull m2 = __ballot(s & 4);
  ull g = bm;
  g &= (s & 1) ? m0 : ~m0;
  g &= (s & 2) ? m1 : ~m1;
  g &= (s & 4) ? m2 : ~m2;
  return g;
}

// ---------------- CSR build: bucket scatter (+deg fused) ----------------
// 8 slices by dst. Pass 1: wave-aggregated LDS histogram + global deg count.
// One reservation per slice per block. Pass 2: wave-aggregated rank/scatter of
// packed (src<<32|dst) into per-slice buckets.

__global__ __launch_bounds__(256) void k_bucket(const int* __restrict__ src,
                                                const int* __restrict__ dst,
                                                ull* __restrict__ bkt,
                                                int* __restrict__ bcnt,
                                                int* __restrict__ deg,
                                                int E, int SL, int cap){
  __shared__ int hist[NSL];
  __shared__ int cur[NSL];
  int t = threadIdx.x;
  int lane = t & 63;
  int chunk = (E + BKT_BLOCKS - 1) / BKT_BLOCKS;
  int e0 = blockIdx.x * chunk;
  int e1 = min(E, e0 + chunk);
  if (t < NSL) hist[t] = 0;
  __syncthreads();
  // pass 1: deg atomics (fire-and-forget) + wave-aggregated slice histogram
  for (int base = e0; base < e1; base += 256){
    int e = base + t;
    bool act = e < e1;
    int d = 0, s = 0;
    if (act){
      d = dst[e];
      s = d / SL;
      atomicAdd(&deg[d], 1);
    }
    ull g = slice_group(act, s);
    if (act && lane == (__ffsll((long long)g) - 1))
      atomicAdd(&hist[s], __popcll(g));
  }
  __syncthreads();
  if (t < NSL){
    int h = hist[t];
    cur[t] = h ? atomicAdd(&bcnt[t], h) : 0;
  }
  __syncthreads();
  // pass 2: wave-aggregated rank + scatter (chunk re-read is L2-hot)
  for (int base = e0; base < e1; base += 256){
    int e = base + t;
    bool act = e < e1;
    int d = 0, s = 0; ull pk = 0;
    if (act){
      d = dst[e];
      s = d / SL;
      pk = ((ull)(unsigned)src[e] << 32) | (unsigned)d;
    }
    ull g = slice_group(act, s);
    int leader = __ffsll((long long)g) - 1;
    int rank = __popcll(g & ((1ull << lane) - 1));
    int bs = 0;
    if (act && lane == leader) bs = atomicAdd(&cur[s], __popcll(g));
    bs = __shfl(bs, leader);
    if (act){
      int pos = bs + rank;
      if (pos < cap) bkt[(size_t)s * cap + pos] = pk;
    }
  }
}

// slice-strided fill: deg counts down to 0; csr lines slice-local
__global__ __launch_bounds__(256) void k_fill2(const ull* __restrict__ bkt,
                                               const int* __restrict__ bcnt,
                                               const int* __restrict__ offs,
                                               int* __restrict__ deg,
                                               int* __restrict__ csr, int cap){
  int s = blockIdx.x & 7;
  int q = blockIdx.x >> 3;
  int cnt = min(bcnt[s], cap);
  const ull* b = bkt + (size_t)s * cap;
  for (int i = q * 256 + threadIdx.x; i < cnt; i += (FILL_BLOCKS / 8) * 256){
    ull pk = b[i];
    int d  = (int)(pk & 0xffffffffu);
    int sr = (int)(pk >> 32);
    int p  = offs[d] + atomicSub(&deg[d], 1) - 1;
    csr[p] = sr;
  }
}

// ---------------- scans (+prep fused into scanC) ----------------

__global__ __launch_bounds__(256) void k_scanA(const int* __restrict__ deg,
                                               int* __restrict__ bsum, int n){
  __shared__ int sm[256];
  int b = blockIdx.x, t = threadIdx.x;
  int base = b * 1024 + t * 4;
  int s = 0;
  #pragma unroll
  for (int u = 0; u < 4; ++u){ int i = base + u; if (i < n) s += deg[i]; }
  sm[t] = s; __syncthreads();
  for (int off = 128; off > 0; off >>= 1){
    if (t < off) sm[t] += sm[t + off];
    __syncthreads();
  }
  if (t == 0) bsum[b] = sm[0];
}

__global__ void k_scanB(const int* __restrict__ bsum, int* __restrict__ bscan,
                        int* __restrict__ offs, int nb, int n){
  if (blockIdx.x == 0 && threadIdx.x == 0){
    int run = 0;
    for (int i = 0; i < nb; ++i){ bscan[i] = run; run += bsum[i]; }
    offs[n] = run;
  }
}

__global__ __launch_bounds__(256) void k_scanC(const int* __restrict__ deg,
                                               const int* __restrict__ bscan,
                                               int* __restrict__ offs,
                                               float* __restrict__ dis,
                                               float* __restrict__ invd, int n){
  __shared__ int sm[256];
  int b = blockIdx.x, t = threadIdx.x;
  int base = b * 1024 + t * 4;
  int v0 = (base + 0 < n) ? deg[base + 0] : 0;
  int v1 = (base + 1 < n) ? deg[base + 1] : 0;
  int v2 = (base + 2 < n) ? deg[base + 2] : 0;
  int v3 = (base + 3 < n) ? deg[base + 3] : 0;
  int ts = v0 + v1 + v2 + v3;
  sm[t] = ts; __syncthreads();
  #pragma unroll
  for (int off = 1; off < 256; off <<= 1){
    int add = (t >= off) ? sm[t - off] : 0;
    __syncthreads();
    sm[t] += add;
    __syncthreads();
  }
  int excl = sm[t] - ts;
  int run = bscan[b] + excl;
  if (base + 0 < n) offs[base + 0] = run; run += v0;
  if (base + 1 < n) offs[base + 1] = run; run += v1;
  if (base + 2 < n) offs[base + 2] = run; run += v2;
  if (base + 3 < n) offs[base + 3] = run; run += v3;
  #pragma unroll
  for (int u = 0; u < 4; ++u){
    int i = base + u;
    if (i < n){
      float d = (float)((u == 0) ? v0 : (u == 1) ? v1 : (u == 2) ? v2 : v3);
      dis[i]  = rsqrtf(d + 1.0f);       // GCN: deg includes self-loop
      invd[i] = 1.0f / fmaxf(d, 1.0f);  // SAGE mean divisor
    }
  }
}

// ---------------- fp32 -> premultiplied fp16 (layer-1 gather of x) ---------
// hh[i] = fp16(dis[i] * x[i]); GCN agg then sums hh and scales once by dis[i].

__global__ __launch_bounds__(256) void k_f2h(const float* __restrict__ in,
                                             const float* __restrict__ dis,
                                             ushort* __restrict__ out, int n4){
  int i = blockIdx.x * 256 + threadIdx.x;
  if (i < n4){
    float4 v = ((const float4*)in)[i];
    float w = dis[i >> 4];
    v.x *= w; v.y *= w; v.z *= w; v.w *= w;
    ((ushort4*)out)[i] = pack_h4(v);
  }
}

// ---------------- Aggregation: 8x8-lane fp16 gather --------------------
// One wave per node. Lane l: group g=l>>3 handles neighbor csr[k+g], features
// (l&7)*8..+7 as ushort8 (16B). Reduce: shfl_xor 8/16/32.
// MODE 0: GCN  (hh premultiplied by dis): out = dis_i * (sum_j hh_j + hh_i)
// MODE 1: SAGE out[i] = (sum_j hh_j) / max(deg,1)

template<int MODE>
__global__ __launch_bounds__(256) void k_agg(const ushort* __restrict__ in,
                                             const int* __restrict__ offs,
                                             const int* __restrict__ csr,
                                             const float* __restrict__ dis,
                                             const float* __restrict__ invd,
                                             float* __restrict__ out, int n){
  int node = (blockIdx.x * 256 + threadIdx.x) >> 6;
  if (node >= n) return;
  int lane = threadIdx.x & 63;
  int g    = lane >> 3;          // neighbor sub-group 0..7
  int fl   = (lane & 7) * 8;     // feature chunk of 8
  int s = offs[node], e = offs[node + 1];

  float acc[8] = {0.f, 0.f, 0.f, 0.f, 0.f, 0.f, 0.f, 0.f};
  #pragma unroll 2
  for (int k = s + g; k < e; k += 8){
    int j = csr[k];
    ushort8v v = *(const ushort8v*)(in + (size_t)j * 64 + fl);
    #pragma unroll
    for (int q = 0; q < 8; ++q)
      acc[q] += __half2float(__ushort_as_half(v[q]));
  }

  // combine the 8 neighbor-groups
  #pragma unroll
  for (int q = 0; q < 8; ++q) acc[q] += __shfl_xor(acc[q], 8);
  #pragma unroll
  for (int q = 0; q < 8; ++q) acc[q] += __shfl_xor(acc[q], 16);
  #pragma unroll
  for (int q = 0; q < 8; ++q) acc[q] += __shfl_xor(acc[q], 32);

  if (g == 0){
    float r[8];
    if (MODE == 0){
      float di = dis[node];
      ushort8v self = *(const ushort8v*)(in + (size_t)node * 64 + fl);
      #pragma unroll
      for (int q = 0; q < 8; ++q)
        r[q] = di * (acc[q] + __half2float(__ushort_as_half(self[q])));
    } else {
      float iv = invd[node];
      #pragma unroll
      for (int q = 0; q < 8; ++q) r[q] = acc[q] * iv;
    }
    float* o = out + (size_t)node * 64 + fl;
    *(float4*)(o + 0) = make_float4(r[0], r[1], r[2], r[3]);
    *(float4*)(o + 4) = make_float4(r[4], r[5], r[6], r[7]);
  }
}

// ---------------- Dense 64x64 GEMM tiles ----------------

__device__ __forceinline__ void stage_A(const float* __restrict__ A,
                                        float (*As)[68], int row0, int n, int t){
  #pragma unroll
  for (int u = 0; u < 4; ++u){
    int q = u * 256 + t;
    int r = q >> 4;
    int c = (q & 15) * 4;
    int gr = row0 + r;
    float4 v = make_float4(0.f, 0.f, 0.f, 0.f);
    if (gr < n) v = *(const float4*)(A + (size_t)gr * 64 + c);
    *(float4*)&As[r][c] = v;
  }
}

__device__ __forceinline__ void stage_W(const float* __restrict__ W,
                                        float (*Ws)[64], int t){
  #pragma unroll
  for (int u = 0; u < 4; ++u){
    int q = u * 256 + t;
    int r = q >> 4;
    int c = (q & 15) * 4;
    *(float4*)&Ws[r][c] = *(const float4*)(W + r * 64 + c);
  }
}

__device__ __forceinline__ void tile_mm(const float (*As)[68], const float (*Ws)[64],
                                        float4 acc[4], int r0, int c0){
  #pragma unroll 2
  for (int k0 = 0; k0 < 64; k0 += 4){
    float4 a0 = *(const float4*)&As[r0+0][k0];
    float4 a1 = *(const float4*)&As[r0+1][k0];
    float4 a2 = *(const float4*)&As[r0+2][k0];
    float4 a3 = *(const float4*)&As[r0+3][k0];
    float4 w0 = *(const float4*)&Ws[k0+0][c0];
    float4 w1 = *(const float4*)&Ws[k0+1][c0];
    float4 w2 = *(const float4*)&Ws[k0+2][c0];
    float4 w3 = *(const float4*)&Ws[k0+3][c0];
    fma4(acc[0], a0.x, w0); fma4(acc[0], a0.y, w1); fma4(acc[0], a0.z, w2); fma4(acc[0], a0.w, w3);
    fma4(acc[1], a1.x, w0); fma4(acc[1], a1.y, w1); fma4(acc[1], a1.z, w2); fma4(acc[1], a1.w, w3);
    fma4(acc[2], a2.x, w0); fma4(acc[2], a2.y, w1); fma4(acc[2], a2.z, w2); fma4(acc[2], a2.w, w3);
    fma4(acc[3], a3.x, w0); fma4(acc[3], a3.y, w1); fma4(acc[3], a3.z, w2); fma4(acc[3], a3.w, w3);
  }
}

// out = act(A @ W + bias)  [+ fp16 mirror if outh != nullptr]
template<bool RELU>
__global__ __launch_bounds__(256, 2) void k_gemm1(const float* __restrict__ A,
                                                  const float* __restrict__ W,
                                                  const float* __restrict__ bias,
                                                  float* __restrict__ out,
                                                  ushort* __restrict__ outh, int n){
  __shared__ __align__(16) float As[64][68];
  __shared__ __align__(16) float Ws[64][64];
  int t = threadIdx.x;
  int row0 = blockIdx.x * 64;
  stage_W(W, Ws, t);
  stage_A(A, As, row0, n, t);
  __syncthreads();
  int r0 = (t >> 4) * 4, c0 = (t & 15) * 4;
  float4 b4 = *(const float4*)(bias + c0);
  float4 acc[4] = {b4, b4, b4, b4};
  tile_mm(As, Ws, acc, r0, c0);
  #pragma unroll
  for (int i = 0; i < 4; ++i){
    int gr = row0 + r0 + i;
    if (gr < n){
      float4 v = acc[i];
      if (RELU){
        v.x = fmaxf(v.x, 0.f); v.y = fmaxf(v.y, 0.f);
        v.z = fmaxf(v.z, 0.f); v.w = fmaxf(v.w, 0.f);
      }
      *(float4*)(out + (size_t)gr * 64 + c0) = v;
      if (outh) *(ushort4*)(outh + (size_t)gr * 64 + c0) = pack_h4(v);
    }
  }
}

// out = act(A @ W1 + B @ W2 + bias + B)   (SAGE layer with residual)
template<bool RELU>
__global__ __launch_bounds__(256, 2) void k_gemm_dual(const float* __restrict__ A,
                                                      const float* __restrict__ B,
                                                      const float* __restrict__ W1,
                                                      const float* __restrict__ W2,
                                                      const float* __restrict__ bias,
                                                      float* __restrict__ out,
                                                      ushort* __restrict__ outh, int n){
  __shared__ __align__(16) float As[64][68];
  __shared__ __align__(16) float Ws1[64][64];
  __shared__ __align__(16) float Ws2[64][64];
  int t = threadIdx.x;
  int row0 = blockIdx.x * 64;
  stage_W(W1, Ws1, t);
  stage_W(W2, Ws2, t);
  stage_A(A, As, row0, n, t);
  __syncthreads();
  int r0 = (t >> 4) * 4, c0 = (t & 15) * 4;
  float4 b4 = *(const float4*)(bias + c0);
  float4 acc[4] = {b4, b4, b4, b4};
  tile_mm(As, Ws1, acc, r0, c0);
  __syncthreads();
  stage_A(B, As, row0, n, t);
  __syncthreads();
  tile_mm(As, Ws2, acc, r0, c0);
  #pragma unroll
  for (int i = 0; i < 4; ++i){
    float4 res = *(const float4*)&As[r0 + i][c0];   // B tile still in LDS
    acc[i].x += res.x; acc[i].y += res.y; acc[i].z += res.z; acc[i].w += res.w;
    if (RELU){
      acc[i].x = fmaxf(acc[i].x, 0.f); acc[i].y = fmaxf(acc[i].y, 0.f);
      acc[i].z = fmaxf(acc[i].z, 0.f); acc[i].w = fmaxf(acc[i].w, 0.f);
    }
    int gr = row0 + r0 + i;
    if (gr < n){
      *(float4*)(out + (size_t)gr * 64 + c0) = acc[i];
      if (outh) *(ushort4*)(outh + (size_t)gr * 64 + c0) = pack_h4(acc[i]);
    }
  }
}

// hh = fp16(dis * relu((A@W1 + B@W2 + b12 + B) @ W3 + b3))
// (SAGE+res fused with lin; fp32 result is dead downstream -> only hh written,
//  premultiplied by dis for the layer-4 GCN gather)
__global__ __launch_bounds__(256, 2) void k_gemm_tri(const float* __restrict__ A,
                                                     const float* __restrict__ B,
                                                     const float* __restrict__ W1,
                                                     const float* __restrict__ W2,
                                                     const float* __restrict__ b12,
                                                     const float* __restrict__ W3,
                                                     const float* __restrict__ b3,
                                                     const float* __restrict__ dis,
                                                     ushort* __restrict__ outh, int n){
  __shared__ __align__(16) float As[64][68];
  __shared__ __align__(16) float Ws1[64][64];
  __shared__ __align__(16) float Ws2[64][64];
  int t = threadIdx.x;
  int row0 = blockIdx.x * 64;
  stage_W(W1, Ws1, t);
  stage_W(W2, Ws2, t);
  stage_A(A, As, row0, n, t);
  __syncthreads();
  int r0 = (t >> 4) * 4, c0 = (t & 15) * 4;
  float4 b4 = *(const float4*)(b12 + c0);
  float4 acc[4] = {b4, b4, b4, b4};
  tile_mm(As, Ws1, acc, r0, c0);
  __syncthreads();
  stage_A(B, As, row0, n, t);
  __syncthreads();
  tile_mm(As, Ws2, acc, r0, c0);
  #pragma unroll
  for (int i = 0; i < 4; ++i){
    float4 res = *(const float4*)&As[r0 + i][c0];   // +B residual
    acc[i].x += res.x; acc[i].y += res.y; acc[i].z += res.z; acc[i].w += res.w;
  }
  __syncthreads();                     // done reading As(B) and Ws1
  #pragma unroll
  for (int i = 0; i < 4; ++i) *(float4*)&As[r0 + i][c0] = acc[i];
  stage_W(W3, Ws1, t);
  __syncthreads();
  float4 bb = *(const float4*)(b3 + c0);
  float4 acc2[4] = {bb, bb, bb, bb};
  tile_mm(As, Ws1, acc2, r0, c0);
  #pragma unroll
  for (int i = 0; i < 4; ++i){
    int gr = row0 + r0 + i;
    if (gr < n){
      float4 v = acc2[i];
      v.x = fmaxf(v.x, 0.f); v.y = fmaxf(v.y, 0.f);
      v.z = fmaxf(v.z, 0.f); v.w = fmaxf(v.w, 0.f);
      float w = dis[gr];
      v.x *= w; v.y *= w; v.z *= w; v.w *= w;
      *(ushort4*)(outh + (size_t)gr * 64 + c0) = pack_h4(v);
    }
  }
}

// ---------------------------------------------------------------------------

extern "C" void kernel_launch(void* const* d_in, const int* in_sizes, int n_in,
                              void* d_out, int out_size, void* d_ws, size_t ws_size,
                              hipStream_t stream){
  const float* x        = (const float*)d_in[0];
  const int*   ei       = (const int*)  d_in[1];
  const float* gcn1_w   = (const float*)d_in[2];
  const float* gcn1_b   = (const float*)d_in[3];
  const float* sage1_lw = (const float*)d_in[4];
  const float* sage1_lb = (const float*)d_in[5];
  const float* sage1_rw = (const float*)d_in[6];
  const float* sage2_lw = (const float*)d_in[7];
  const float* sage2_lb = (const float*)d_in[8];
  const float* sage2_rw = (const float*)d_in[9];
  const float* lin_w    = (const float*)d_in[10];
  const float* lin_b    = (const float*)d_in[11];
  const float* gcn2_w   = (const float*)d_in[12];
  const float* gcn2_b   = (const float*)d_in[13];
  float* out = (float*)d_out;

  const int n = in_sizes[0] / 64;
  const int E = in_sizes[1] / 2;
  const int* src = ei;
  const int* dst = ei + E;
  const int SL  = (n + NSL - 1) / NSL;   // dst-slice width
  const int cap = E / 4;                 // per-slice bucket capacity (~2x expected)

  // workspace carve (~70 MB); bkt aliases bufA (dead during CSR build)
  uintptr_t p = (uintptr_t)d_ws;
  auto alloc = [&](size_t b) -> void* {
    p = (p + 255) & ~(uintptr_t)255;
    void* r = (void*)p; p += b; return r;
  };
  float*  bufA = (float*)alloc((size_t)n * 64 * 4);
  float*  bufB = (float*)alloc((size_t)n * 64 * 4);
  ushort* hh   = (ushort*)alloc((size_t)n * 64 * 2);  // fp16 gather mirror
  int*    deg  = (int*)  alloc((size_t)(n + 8) * 4);  // + bcnt(8) tail, one memset
  int*    bcnt = deg + n;
  int*    offs = (int*)  alloc((size_t)(n + 1) * 4);
  const int NB = (n + 1023) / 1024;
  int*    bsum  = (int*) alloc((size_t)NB * 4);
  int*    bscan = (int*) alloc((size_t)NB * 4);
  int*    csr   = (int*) alloc((size_t)E * 4);
  float*  dis   = (float*)alloc((size_t)n * 4);
  float*  invd  = (float*)alloc((size_t)n * 4);
  ull*    bkt   = (ull*)bufA;            // 8 * cap * 8B = 20 MB < bufA (25.6 MB)

  hipMemsetAsync(deg, 0, (size_t)(n + 8) * 4, stream);

  const int gAgg = (n + 3) / 4;      // one wave per node, 4 waves/block
  const int gG = (n + 63) / 64;      // 64-row GEMM tiles
  const int gC = (n * 16 + 255) / 256;

  // CSR build: bucket scatter(+deg) -> scan(+prep) -> slice-strided fill
  k_bucket<<<BKT_BLOCKS, 256, 0, stream>>>(src, dst, bkt, bcnt, deg, E, SL, cap);
  k_scanA <<<NB, 256, 0, stream>>>(deg, bsum, n);
  k_scanB <<<1, 1, 0, stream>>>(bsum, bscan, offs, NB, n);
  k_scanC <<<NB, 256, 0, stream>>>(deg, bscan, offs, dis, invd, n);
  k_fill2 <<<FILL_BLOCKS, 256, 0, stream>>>(bkt, bcnt, offs, deg, csr, cap);

  // Layer 1: h1 = relu(GCNagg(x) @ gcn1_w + b)           -> d_out (+hh)
  k_f2h<<<gC, 256, 0, stream>>>(x, dis, hh, n * 16);             // hh = dis*x
  k_agg<0><<<gAgg, 256, 0, stream>>>(hh, offs, csr, dis, invd, bufA, n);
  k_gemm1<true><<<gG, 256, 0, stream>>>(bufA, gcn1_w, gcn1_b, out, hh, n);

  // Layer 2: h2 = relu(mean(h1)@Wl + bl + h1@Wr + h1)    -> bufB (+hh)
  k_agg<1><<<gAgg, 256, 0, stream>>>(hh, offs, csr, dis, invd, bufA, n);
  k_gemm_dual<true><<<gG, 256, 0, stream>>>(bufA, out, sage1_lw, sage1_rw, sage1_lb, bufB, hh, n);

  // Layer 3 (fused 3a+3b): hh = dis*relu((mean(h2)@Wl2+bl2+h2@Wr2+h2)@lin_w+lin_b)
  k_agg<1><<<gAgg, 256, 0, stream>>>(hh, offs, csr, dis, invd, bufA, n);
  k_gemm_tri<<<gG, 256, 0, stream>>>(bufA, bufB, sage2_lw, sage2_rw, sage2_lb,
                                     lin_w, lin_b, dis, hh, n);

  // Layer 4: out = GCNagg(h4) @ gcn2_w + gcn2_b          -> d_out
  k_agg<0><<<gAgg, 256, 0, stream>>>(hh, offs, csr, dis, invd, bufA, n);
  k_gemm1<false><<<gG, 256, 0, stream>>>(bufA, gcn2_w, gcn2_b, out, (ushort*)nullptr, n);
}